// Round 1
// baseline (294.874 us; speedup 1.0000x reference)
//
#include <hip/hip_runtime.h>
#include <hip/hip_bf16.h>

#define B_ 4
#define N_ 2048
#define D_ 1024
#define H_ 8
#define HD_ 128

typedef __attribute__((ext_vector_type(4))) float f32x4;
typedef __attribute__((ext_vector_type(8))) short bf16x8;

__device__ __forceinline__ short f2bf(float f) {
    unsigned u = __builtin_bit_cast(unsigned, f);
    u = (u + 0x7FFFu + ((u >> 16) & 1u)) >> 16;   // round-to-nearest-even
    return (short)u;
}

// ---------------------------------------------------------------------------
// Kernel 1: sr[b,h,j] = sum_{c<128} leaky((h @ Wr^T)[b,j,h*128+c]) * att_r[c]
// One block = 4 waves; wave computes a 16x128 tile of fr via 8 MFMA accum
// tiles (16x16x32 bf16), fr never hits memory.
// ---------------------------------------------------------------------------
__global__ __launch_bounds__(256) void k_proj_sr(
    const float* __restrict__ h, const float* __restrict__ Wr,
    const float* __restrict__ att_r, float* __restrict__ sr)
{
    const int lane = threadIdx.x & 63;
    const int wave = threadIdx.x >> 6;
    const int cc   = lane & 15;     // A-row / B-col within 16-tile
    const int g    = lane >> 4;     // k-group (8 consecutive k each)
    const int jt   = blockIdx.x;    // 0..31
    const int head = blockIdx.y;    // 0..7
    const int b    = blockIdx.z;    // 0..3
    const int jbase = jt * 64 + wave * 16;

    const float* arow  = h  + ((size_t)(b * N_ + jbase + cc)) * D_;
    const float* wbase = Wr + ((size_t)(head * HD_ + cc)) * D_;

    f32x4 acc[8];
#pragma unroll
    for (int t = 0; t < 8; ++t) acc[t] = (f32x4){0.f, 0.f, 0.f, 0.f};

    for (int k0 = 0; k0 < D_; k0 += 32) {
        const int kk = k0 + g * 8;
        float4 a0 = *(const float4*)(arow + kk);
        float4 a1 = *(const float4*)(arow + kk + 4);
        bf16x8 af;
        af[0] = f2bf(a0.x); af[1] = f2bf(a0.y); af[2] = f2bf(a0.z); af[3] = f2bf(a0.w);
        af[4] = f2bf(a1.x); af[5] = f2bf(a1.y); af[6] = f2bf(a1.z); af[7] = f2bf(a1.w);
#pragma unroll
        for (int t = 0; t < 8; ++t) {
            const float* wrow = wbase + (size_t)t * 16 * D_ + kk;
            float4 b0 = *(const float4*)(wrow);
            float4 b1 = *(const float4*)(wrow + 4);
            bf16x8 bf;
            bf[0] = f2bf(b0.x); bf[1] = f2bf(b0.y); bf[2] = f2bf(b0.z); bf[3] = f2bf(b0.w);
            bf[4] = f2bf(b1.x); bf[5] = f2bf(b1.y); bf[6] = f2bf(b1.z); bf[7] = f2bf(b1.w);
            acc[t] = __builtin_amdgcn_mfma_f32_16x16x32_bf16(af, bf, acc[t], 0, 0, 0);
        }
    }

    // Epilogue: C/D layout is col = lane&15, row = (lane>>4)*4 + reg.
    // acc[t][r] = fr[j_local = g*4+r][col = t*16+cc]
    float ar[8];
#pragma unroll
    for (int t = 0; t < 8; ++t) ar[t] = att_r[t * 16 + cc];

#pragma unroll
    for (int r = 0; r < 4; ++r) {
        float p = 0.f;
#pragma unroll
        for (int t = 0; t < 8; ++t) {
            float v = acc[t][r];
            v = v > 0.f ? v : 0.01f * v;   // leaky
            p += v * ar[t];
        }
        // reduce over the 16 lanes (low 4 bits) sharing a row
        p += __shfl_xor(p, 1); p += __shfl_xor(p, 2);
        p += __shfl_xor(p, 4); p += __shfl_xor(p, 8);
        if (cc == 0)
            sr[(size_t)(b * H_ + head) * N_ + jbase + g * 4 + r] = p;
    }
}

// ---------------------------------------------------------------------------
// Kernel 2: w[bh, :] = softmax(sr[bh, :]) over N=2048, one block per (b,h)
// ---------------------------------------------------------------------------
__global__ __launch_bounds__(256) void k_softmax(
    const float* __restrict__ sr, float* __restrict__ w)
{
    const int bh = blockIdx.x;
    const int tid = threadIdx.x;
    const int lane = tid & 63, wave = tid >> 6;
    const float* s = sr + (size_t)bh * N_;
    float* o = w + (size_t)bh * N_;

    float v[8];
    float mx = -1e30f;
#pragma unroll
    for (int i = 0; i < 8; ++i) { v[i] = s[tid + i * 256]; mx = fmaxf(mx, v[i]); }
#pragma unroll
    for (int m = 1; m < 64; m <<= 1) mx = fmaxf(mx, __shfl_xor(mx, m));

    __shared__ float rmax[4], rsum[4];
    if (lane == 0) rmax[wave] = mx;
    __syncthreads();
    mx = fmaxf(fmaxf(rmax[0], rmax[1]), fmaxf(rmax[2], rmax[3]));

    float sum = 0.f;
#pragma unroll
    for (int i = 0; i < 8; ++i) { v[i] = expf(v[i] - mx); sum += v[i]; }
#pragma unroll
    for (int m = 1; m < 64; m <<= 1) sum += __shfl_xor(sum, m);
    if (lane == 0) rsum[wave] = sum;
    __syncthreads();
    sum = rsum[0] + rsum[1] + rsum[2] + rsum[3];
    const float inv = 1.f / sum;
#pragma unroll
    for (int i = 0; i < 8; ++i) o[tid + i * 256] = v[i] * inv;
}

// ---------------------------------------------------------------------------
// Kernel 3: partial hbar[jc][b,h,d] = sum_{j in chunk jc} w[b,h,j] * h[b,j,d]
// (deterministic: partials + separate reduce, no fp atomics)
// ---------------------------------------------------------------------------
__global__ __launch_bounds__(256) void k_hbar_partial(
    const float* __restrict__ h, const float* __restrict__ w,
    float* __restrict__ hp)
{
    const int dc = blockIdx.x;   // 0..3   (256 d each)
    const int jc = blockIdx.y;   // 0..7   (256 j each)
    const int b  = blockIdx.z;   // 0..3
    const int tid = threadIdx.x;
    const int d = dc * 256 + tid;

    __shared__ float wl[8][256];
#pragma unroll
    for (int hh = 0; hh < 8; ++hh)
        wl[hh][tid] = w[(size_t)(b * H_ + hh) * N_ + jc * 256 + tid];
    __syncthreads();

    float acc[8] = {0.f, 0.f, 0.f, 0.f, 0.f, 0.f, 0.f, 0.f};
    const float* hp0 = h + ((size_t)(b * N_ + jc * 256)) * D_ + d;
    for (int jj = 0; jj < 256; ++jj) {
        float hv = hp0[(size_t)jj * D_];
#pragma unroll
        for (int hh = 0; hh < 8; ++hh) acc[hh] += wl[hh][jj] * hv;
    }
#pragma unroll
    for (int hh = 0; hh < 8; ++hh)
        hp[((size_t)(jc * 32) + b * 8 + hh) * D_ + d] = acc[hh];
}

__global__ __launch_bounds__(256) void k_hbar_reduce(
    const float* __restrict__ hp, float* __restrict__ hbar)
{
    const int i = blockIdx.x * 256 + threadIdx.x;  // 0..32767
    float s = 0.f;
#pragma unroll
    for (int jc = 0; jc < 8; ++jc) s += hp[(size_t)jc * 32768 + i];
    hbar[i] = s;
}

// ---------------------------------------------------------------------------
// Kernel 4: ctx[b, head*128+d'] = sum_e hbar[b,head,e] * Wr[head*128+d', e]
// one wave per output element
// ---------------------------------------------------------------------------
__global__ __launch_bounds__(256) void k_ctx(
    const float* __restrict__ hbar, const float* __restrict__ Wr,
    float* __restrict__ ctx)
{
    const int o = blockIdx.x * 4 + (threadIdx.x >> 6);   // 0..4095
    const int lane = threadIdx.x & 63;
    const int b = o >> 10, rem = o & 1023;
    const int head = rem >> 7;
    const float* x  = hbar + (size_t)(b * H_ + head) * D_;
    const float* wr = Wr + (size_t)rem * D_;   // rem = head*128 + d'
    float s = 0.f;
#pragma unroll
    for (int it = 0; it < 4; ++it) {
        float4 xv = *(const float4*)(x + it * 256 + lane * 4);
        float4 wv = *(const float4*)(wr + it * 256 + lane * 4);
        s += xv.x * wv.x + xv.y * wv.y + xv.z * wv.z + xv.w * wv.w;
    }
#pragma unroll
    for (int m = 1; m < 64; m <<= 1) s += __shfl_xor(s, m);
    if (lane == 0) ctx[o] = s;
}

// ---------------------------------------------------------------------------
// Kernel 5: fvec[b, o] = sum_e ctx[b,e] * Wf[o,e]
// ---------------------------------------------------------------------------
__global__ __launch_bounds__(256) void k_fvec(
    const float* __restrict__ ctx, const float* __restrict__ Wf,
    float* __restrict__ fvec)
{
    const int o = blockIdx.x * 4 + (threadIdx.x >> 6);   // 0..4095
    const int lane = threadIdx.x & 63;
    const int b = o >> 10, orow = o & 1023;
    const float* x  = ctx + (size_t)b * D_;
    const float* wf = Wf + (size_t)orow * D_;
    float s = 0.f;
#pragma unroll
    for (int it = 0; it < 4; ++it) {
        float4 xv = *(const float4*)(x + it * 256 + lane * 4);
        float4 wv = *(const float4*)(wf + it * 256 + lane * 4);
        s += xv.x * wv.x + xv.y * wv.y + xv.z * wv.z + xv.w * wv.w;
    }
#pragma unroll
    for (int m = 1; m < 64; m <<= 1) s += __shfl_xor(s, m);
    if (lane == 0) fvec[o] = s;
}

// ---------------------------------------------------------------------------
// Kernel 6: out = LayerNorm(h + fvec[b]) * gamma + beta, one block per row
// ---------------------------------------------------------------------------
__global__ __launch_bounds__(256) void k_ln(
    const float* __restrict__ h, const float* __restrict__ fvec,
    const float* __restrict__ gamma, const float* __restrict__ beta,
    float* __restrict__ out)
{
    const int row = blockIdx.x;        // b*2048 + n
    const int b = row >> 11;
    const int tid = threadIdx.x;
    const int lane = tid & 63, wave = tid >> 6;

    float4 hv = *(const float4*)(h + (size_t)row * D_ + tid * 4);
    float4 fv = *(const float4*)(fvec + (size_t)b * D_ + tid * 4);
    const float y0 = hv.x + fv.x, y1 = hv.y + fv.y;
    const float y2 = hv.z + fv.z, y3 = hv.w + fv.w;

    float s = y0 + y1 + y2 + y3;
    float q = y0 * y0 + y1 * y1 + y2 * y2 + y3 * y3;
#pragma unroll
    for (int m = 1; m < 64; m <<= 1) { s += __shfl_xor(s, m); q += __shfl_xor(q, m); }

    __shared__ float rs[4], rq[4];
    if (lane == 0) { rs[wave] = s; rq[wave] = q; }
    __syncthreads();
    s = rs[0] + rs[1] + rs[2] + rs[3];
    q = rq[0] + rq[1] + rq[2] + rq[3];

    const float mu  = s * (1.f / D_);
    const float var = q * (1.f / D_) - mu * mu;
    const float inv = rsqrtf(var + 1e-5f);

    float4 gv = *(const float4*)(gamma + tid * 4);
    float4 bv = *(const float4*)(beta + tid * 4);
    float4 ov;
    ov.x = (y0 - mu) * inv * gv.x + bv.x;
    ov.y = (y1 - mu) * inv * gv.y + bv.y;
    ov.z = (y2 - mu) * inv * gv.z + bv.z;
    ov.w = (y3 - mu) * inv * gv.w + bv.w;
    *(float4*)(out + (size_t)row * D_ + tid * 4) = ov;
}

// ---------------------------------------------------------------------------
extern "C" void kernel_launch(void* const* d_in, const int* in_sizes, int n_in,
                              void* d_out, int out_size, void* d_ws, size_t ws_size,
                              hipStream_t stream) {
    const float* h     = (const float*)d_in[0];
    // d_in[1] = Wl  : dead (softmax over additive scores cancels sl)
    const float* Wr    = (const float*)d_in[2];
    // d_in[3] = att_l : dead
    const float* att_r = (const float*)d_in[4];
    const float* Wf    = (const float*)d_in[5];
    const float* gamma = (const float*)d_in[6];
    const float* beta  = (const float*)d_in[7];
    float* out = (float*)d_out;

    char* ws = (char*)d_ws;
    float* sr   = (float*)(ws);                 // B*H*N      = 256 KB
    float* w    = (float*)(ws + 262144);        // B*H*N      = 256 KB
    float* hp   = (float*)(ws + 524288);        // 8*B*H*D    = 1 MB
    float* hbar = (float*)(ws + 1572864);       // B*H*D      = 128 KB
    float* ctx  = (float*)(ws + 1703936);       // B*D        = 16 KB
    float* fvec = (float*)(ws + 1720320);       // B*D        = 16 KB

    k_proj_sr<<<dim3(N_ / 64, H_, B_), 256, 0, stream>>>(h, Wr, att_r, sr);
    k_softmax<<<B_ * H_, 256, 0, stream>>>(sr, w);
    k_hbar_partial<<<dim3(4, 8, 4), 256, 0, stream>>>(h, w, hp);
    k_hbar_reduce<<<128, 256, 0, stream>>>(hp, hbar);
    k_ctx<<<1024, 256, 0, stream>>>(hbar, Wr, ctx);
    k_fvec<<<1024, 256, 0, stream>>>(ctx, Wf, fvec);
    k_ln<<<B_ * N_, 256, 0, stream>>>(h, fvec, gamma, beta, out);
}

// Round 2
// 79.684 us; speedup vs baseline: 3.7006x; 3.7006x over previous
//
#include <hip/hip_runtime.h>
#include <hip/hip_bf16.h>

#define B_ 4
#define N_ 2048
#define D_ 1024
#define H_ 8
#define HD_ 128

typedef __attribute__((ext_vector_type(4))) float f32x4;
typedef __attribute__((ext_vector_type(8))) short bf16x8;

__device__ __forceinline__ short f2bf(float f) {
    unsigned u = __builtin_bit_cast(unsigned, f);
    u = (u + 0x7FFFu + ((u >> 16) & 1u)) >> 16;   // round-to-nearest-even
    return (short)u;
}

typedef const __attribute__((address_space(1))) void* gas_t;
typedef __attribute__((address_space(3))) void* las_t;

__device__ __forceinline__ void gload16(const void* g, void* l) {
    // lane i's 16B from g(lane) -> ldsbase + i*16 (wave-uniform LDS base)
    __builtin_amdgcn_global_load_lds((gas_t)g, (las_t)l, 16, 0, 0);
}

// ---------------------------------------------------------------------------
// Kernel 0: fp32 -> bf16 pack, 8 elems/thread
// ---------------------------------------------------------------------------
__global__ __launch_bounds__(256) void k_cvt(
    const float* __restrict__ src, short* __restrict__ dst, int n8)
{
    const int i = blockIdx.x * 256 + threadIdx.x;
    if (i >= n8) return;
    float4 a = ((const float4*)src)[i * 2];
    float4 b = ((const float4*)src)[i * 2 + 1];
    bf16x8 o;
    o[0] = f2bf(a.x); o[1] = f2bf(a.y); o[2] = f2bf(a.z); o[3] = f2bf(a.w);
    o[4] = f2bf(b.x); o[5] = f2bf(b.y); o[6] = f2bf(b.z); o[7] = f2bf(b.w);
    ((bf16x8*)dst)[i] = o;
}

// ---------------------------------------------------------------------------
// Kernel 1: m97-structure GEMM computing fr = h @ Wr^T tile-wise (bf16 MFMA),
// fused epilogue: sr[b,head,j] = sum_c leaky(fr[j, head*128+c]) * att_r[c].
// Grid: (M/128 = 64, heads = 8). Block 256 thr = 4 waves (2x2 of 64x64).
// ---------------------------------------------------------------------------
__global__ __launch_bounds__(256) void k_proj_sr(
    const short* __restrict__ hb, const short* __restrict__ wrb,
    const float* __restrict__ att_r, float* __restrict__ sr)
{
    __shared__ short sA[128 * 32];     // 8 KB, row-major [128][32]
    __shared__ short sB[128 * 32];     // 8 KB
    __shared__ float part[2][128];

    const int tid  = threadIdx.x;
    const int lane = tid & 63;
    const int wave = tid >> 6;
    const int cc   = lane & 15;
    const int g    = lane >> 4;
    const int wr   = wave >> 1;        // wave row (0..1) -> rows wr*64..+64
    const int wc   = wave & 1;         // wave col (0..1) -> cols wc*64..+64
    const int rowBase = blockIdx.x * 128;   // global j-row base (0..8191)
    const int head    = blockIdx.y;

    // staging geometry: wave covers LDS bytes [(wave*2+q)*1024, +1024)
    const int r0q0 = (wave * 2) * 16 + (lane >> 2);   // row_local for q=0
    const int colb = (lane & 3) * 8;                  // k-offset (bf16 elems)
    const short* gA0 = hb  + (size_t)(rowBase + r0q0) * D_ + colb;
    const short* gB0 = wrb + (size_t)(head * HD_ + r0q0) * D_ + colb;
    char* lA = (char*)sA + (size_t)(wave * 2) * 1024;
    char* lB = (char*)sB + (size_t)(wave * 2) * 1024;

    f32x4 acc[4][4];
#pragma unroll
    for (int m = 0; m < 4; ++m)
#pragma unroll
        for (int n = 0; n < 4; ++n) acc[m][n] = (f32x4){0.f, 0.f, 0.f, 0.f};

    for (int k0 = 0; k0 < D_; k0 += 32) {
        // stage A,B tiles (each wave: 2+2 issues of 1024B)
        gload16(gA0 + k0,            lA);
        gload16(gA0 + k0 + 16 * D_,  lA + 1024);
        gload16(gB0 + k0,            lB);
        gload16(gB0 + k0 + 16 * D_,  lB + 1024);
        __syncthreads();   // compiler drains vmcnt(0) before barrier

        bf16x8 aF[4], bF[4];
#pragma unroll
        for (int m = 0; m < 4; ++m)
            aF[m] = *(const bf16x8*)(sA + ((wr * 64 + m * 16 + cc) * 32 + g * 8));
#pragma unroll
        for (int n = 0; n < 4; ++n)
            bF[n] = *(const bf16x8*)(sB + ((wc * 64 + n * 16 + cc) * 32 + g * 8));
#pragma unroll
        for (int m = 0; m < 4; ++m)
#pragma unroll
            for (int n = 0; n < 4; ++n)
                acc[m][n] = __builtin_amdgcn_mfma_f32_16x16x32_bf16(
                    aF[m], bF[n], acc[m][n], 0, 0, 0);
        __syncthreads();   // protect LDS before next stage
    }

    // Epilogue: row = rowBase + wr*64 + m*16 + g*4 + reg,
    //           col_in_head = wc*64 + n*16 + cc
    float ar[4];
#pragma unroll
    for (int n = 0; n < 4; ++n) ar[n] = att_r[wc * 64 + n * 16 + cc];

#pragma unroll
    for (int m = 0; m < 4; ++m) {
#pragma unroll
        for (int r = 0; r < 4; ++r) {
            float p = 0.f;
#pragma unroll
            for (int n = 0; n < 4; ++n) {
                float v = acc[m][n][r];
                v = v > 0.f ? v : 0.01f * v;    // leaky
                p += v * ar[n];
            }
            p += __shfl_xor(p, 1); p += __shfl_xor(p, 2);
            p += __shfl_xor(p, 4); p += __shfl_xor(p, 8);
            if (cc == 0) part[wc][wr * 64 + m * 16 + g * 4 + r] = p;
        }
    }
    __syncthreads();
    if (tid < 128) {
        const int grow = rowBase + tid;
        const int b = grow >> 11, j = grow & (N_ - 1);
        sr[(size_t)(b * H_ + head) * N_ + j] = part[0][tid] + part[1][tid];
    }
}

// ---------------------------------------------------------------------------
// Kernel 2: w[bh, :] = softmax(sr[bh, :]) over N=2048, one block per (b,h)
// ---------------------------------------------------------------------------
__global__ __launch_bounds__(256) void k_softmax(
    const float* __restrict__ sr, float* __restrict__ w)
{
    const int bh = blockIdx.x;
    const int tid = threadIdx.x;
    const int lane = tid & 63, wave = tid >> 6;
    const float* s = sr + (size_t)bh * N_;
    float* o = w + (size_t)bh * N_;

    float v[8];
    float mx = -1e30f;
#pragma unroll
    for (int i = 0; i < 8; ++i) { v[i] = s[tid + i * 256]; mx = fmaxf(mx, v[i]); }
#pragma unroll
    for (int m = 1; m < 64; m <<= 1) mx = fmaxf(mx, __shfl_xor(mx, m));

    __shared__ float rmax[4], rsum[4];
    if (lane == 0) rmax[wave] = mx;
    __syncthreads();
    mx = fmaxf(fmaxf(rmax[0], rmax[1]), fmaxf(rmax[2], rmax[3]));

    float sum = 0.f;
#pragma unroll
    for (int i = 0; i < 8; ++i) { v[i] = expf(v[i] - mx); sum += v[i]; }
#pragma unroll
    for (int m = 1; m < 64; m <<= 1) sum += __shfl_xor(sum, m);
    if (lane == 0) rsum[wave] = sum;
    __syncthreads();
    sum = rsum[0] + rsum[1] + rsum[2] + rsum[3];
    const float inv = 1.f / sum;
#pragma unroll
    for (int i = 0; i < 8; ++i) o[tid + i * 256] = v[i] * inv;
}

// ---------------------------------------------------------------------------
// Kernel 3: partial hbar[jc][b,h,d] = sum_{j in chunk jc} w[b,h,j] * h[b,j,d]
// ---------------------------------------------------------------------------
__global__ __launch_bounds__(256) void k_hbar_partial(
    const float* __restrict__ h, const float* __restrict__ w,
    float* __restrict__ hp)
{
    const int dc = blockIdx.x;   // 0..3
    const int jc = blockIdx.y;   // 0..7
    const int b  = blockIdx.z;   // 0..3
    const int tid = threadIdx.x;
    const int d = dc * 256 + tid;

    __shared__ float wl[8][256];
#pragma unroll
    for (int hh = 0; hh < 8; ++hh)
        wl[hh][tid] = w[(size_t)(b * H_ + hh) * N_ + jc * 256 + tid];
    __syncthreads();

    float acc[8] = {0.f, 0.f, 0.f, 0.f, 0.f, 0.f, 0.f, 0.f};
    const float* hp0 = h + ((size_t)(b * N_ + jc * 256)) * D_ + d;
    for (int jj = 0; jj < 256; ++jj) {
        float hv = hp0[(size_t)jj * D_];
#pragma unroll
        for (int hh = 0; hh < 8; ++hh) acc[hh] += wl[hh][jj] * hv;
    }
#pragma unroll
    for (int hh = 0; hh < 8; ++hh)
        hp[((size_t)(jc * 32) + b * 8 + hh) * D_ + d] = acc[hh];
}

__global__ __launch_bounds__(256) void k_hbar_reduce(
    const float* __restrict__ hp, float* __restrict__ hbar)
{
    const int i = blockIdx.x * 256 + threadIdx.x;  // 0..32767
    float s = 0.f;
#pragma unroll
    for (int jc = 0; jc < 8; ++jc) s += hp[(size_t)jc * 32768 + i];
    hbar[i] = s;
}

// ---------------------------------------------------------------------------
// Kernel 4: ctx[b, head*128+d'] = sum_e hbar[b,head,e] * Wr[head*128+d', e]
// ---------------------------------------------------------------------------
__global__ __launch_bounds__(256) void k_ctx(
    const float* __restrict__ hbar, const float* __restrict__ Wr,
    float* __restrict__ ctx)
{
    const int o = blockIdx.x * 4 + (threadIdx.x >> 6);   // 0..4095
    const int lane = threadIdx.x & 63;
    const int b = o >> 10, rem = o & 1023;
    const int head = rem >> 7;
    const float* x  = hbar + (size_t)(b * H_ + head) * D_;
    const float* wr = Wr + (size_t)rem * D_;
    float s = 0.f;
#pragma unroll
    for (int it = 0; it < 4; ++it) {
        float4 xv = *(const float4*)(x + it * 256 + lane * 4);
        float4 wv = *(const float4*)(wr + it * 256 + lane * 4);
        s += xv.x * wv.x + xv.y * wv.y + xv.z * wv.z + xv.w * wv.w;
    }
#pragma unroll
    for (int m = 1; m < 64; m <<= 1) s += __shfl_xor(s, m);
    if (lane == 0) ctx[o] = s;
}

// ---------------------------------------------------------------------------
// Kernel 5: fvec[b, o] = sum_e ctx[b,e] * Wf[o,e]
// ---------------------------------------------------------------------------
__global__ __launch_bounds__(256) void k_fvec(
    const float* __restrict__ ctx, const float* __restrict__ Wf,
    float* __restrict__ fvec)
{
    const int o = blockIdx.x * 4 + (threadIdx.x >> 6);   // 0..4095
    const int lane = threadIdx.x & 63;
    const int b = o >> 10, orow = o & 1023;
    const float* x  = ctx + (size_t)b * D_;
    const float* wf = Wf + (size_t)orow * D_;
    float s = 0.f;
#pragma unroll
    for (int it = 0; it < 4; ++it) {
        float4 xv = *(const float4*)(x + it * 256 + lane * 4);
        float4 wv = *(const float4*)(wf + it * 256 + lane * 4);
        s += xv.x * wv.x + xv.y * wv.y + xv.z * wv.z + xv.w * wv.w;
    }
#pragma unroll
    for (int m = 1; m < 64; m <<= 1) s += __shfl_xor(s, m);
    if (lane == 0) fvec[o] = s;
}

// ---------------------------------------------------------------------------
// Kernel 6: out = LayerNorm(h + fvec[b]) * gamma + beta, one block per row.
// Runs LAST: overwrites d_out (which held the bf16 scratch copies).
// ---------------------------------------------------------------------------
__global__ __launch_bounds__(256) void k_ln(
    const float* __restrict__ h, const float* __restrict__ fvec,
    const float* __restrict__ gamma, const float* __restrict__ beta,
    float* __restrict__ out)
{
    const int row = blockIdx.x;
    const int b = row >> 11;
    const int tid = threadIdx.x;
    const int lane = tid & 63, wave = tid >> 6;

    float4 hv = *(const float4*)(h + (size_t)row * D_ + tid * 4);
    float4 fv = *(const float4*)(fvec + (size_t)b * D_ + tid * 4);
    const float y0 = hv.x + fv.x, y1 = hv.y + fv.y;
    const float y2 = hv.z + fv.z, y3 = hv.w + fv.w;

    float s = y0 + y1 + y2 + y3;
    float q = y0 * y0 + y1 * y1 + y2 * y2 + y3 * y3;
#pragma unroll
    for (int m = 1; m < 64; m <<= 1) { s += __shfl_xor(s, m); q += __shfl_xor(q, m); }

    __shared__ float rs[4], rq[4];
    if (lane == 0) { rs[wave] = s; rq[wave] = q; }
    __syncthreads();
    s = rs[0] + rs[1] + rs[2] + rs[3];
    q = rq[0] + rq[1] + rq[2] + rq[3];

    const float mu  = s * (1.f / D_);
    const float var = q * (1.f / D_) - mu * mu;
    const float inv = rsqrtf(var + 1e-5f);

    float4 gv = *(const float4*)(gamma + tid * 4);
    float4 bv = *(const float4*)(beta + tid * 4);
    float4 ov;
    ov.x = (y0 - mu) * inv * gv.x + bv.x;
    ov.y = (y1 - mu) * inv * gv.y + bv.y;
    ov.z = (y2 - mu) * inv * gv.z + bv.z;
    ov.w = (y3 - mu) * inv * gv.w + bv.w;
    *(float4*)(out + (size_t)row * D_ + tid * 4) = ov;
}

// ---------------------------------------------------------------------------
extern "C" void kernel_launch(void* const* d_in, const int* in_sizes, int n_in,
                              void* d_out, int out_size, void* d_ws, size_t ws_size,
                              hipStream_t stream) {
    const float* h     = (const float*)d_in[0];
    // d_in[1] = Wl  : dead (softmax over additive scores cancels sl)
    const float* Wr    = (const float*)d_in[2];
    // d_in[3] = att_l : dead
    const float* att_r = (const float*)d_in[4];
    const float* Wf    = (const float*)d_in[5];
    const float* gamma = (const float*)d_in[6];
    const float* beta  = (const float*)d_in[7];
    float* out = (float*)d_out;

    // bf16 scratch copies live in d_out (32 MB); overwritten last by k_ln.
    short* hb  = (short*)d_out;                          // 8M bf16 = 16 MB
    short* wrb = (short*)((char*)d_out + 16 * 1024 * 1024); // 1M bf16 = 2 MB

    char* ws = (char*)d_ws;
    float* sr   = (float*)(ws);                 // B*H*N      = 256 KB
    float* w    = (float*)(ws + 262144);        // B*H*N      = 256 KB
    float* hp   = (float*)(ws + 524288);        // 8*B*H*D    = 1 MB
    float* hbar = (float*)(ws + 1572864);       // B*H*D      = 128 KB
    float* ctx  = (float*)(ws + 1703936);       // B*D        = 16 KB
    float* fvec = (float*)(ws + 1720320);       // B*D        = 16 KB

    k_cvt<<<4096, 256, 0, stream>>>(h,  hb,  (B_ * N_ * D_) / 8);
    k_cvt<<<512,  256, 0, stream>>>(Wr, wrb, (D_ * D_) / 8);
    k_proj_sr<<<dim3((B_ * N_) / 128, H_), 256, 0, stream>>>(hb, wrb, att_r, sr);
    k_softmax<<<B_ * H_, 256, 0, stream>>>(sr, w);
    k_hbar_partial<<<dim3(4, 8, 4), 256, 0, stream>>>(h, w, hp);
    k_hbar_reduce<<<128, 256, 0, stream>>>(hp, hbar);
    k_ctx<<<1024, 256, 0, stream>>>(hbar, Wr, ctx);
    k_fvec<<<1024, 256, 0, stream>>>(ctx, Wf, fvec);
    k_ln<<<B_ * N_, 256, 0, stream>>>(h, fvec, gamma, beta, out);
}